// Round 4
// baseline (293.985 us; speedup 1.0000x reference)
//
#include <hip/hip_runtime.h>
#include <stdint.h>

// Problem constants
#define NB       64
#define FIN      12
#define HD       64
#define NHEADS   4
#define DHEAD    16
#define NLAYERS  3
#define ODIM     128
#define LN_EPS   1e-5f
#define BTOT     8192

#define NTH      256
#define NW       (NLAYERS * 4)
#define WFRAG    4096  // u16 per packed weight
#define WIN_U16  2048  // packed W_in^T (zero-padded K=32)
#define NTILES   10    // band tiles (|tj-ti|<=1) of the 4x4 tile grid
#define MSK_U32  (NTILES * 64 * 2)   // 1280 u32 of f16 0/1 fragment masks

// Padded node-row stride: 20 u16 = 40 B = 10 dwords. Spreads the V-gather over
// all 32 banks (was 8 banks / 4-way at STR=16) and de-aliases the m/m+4 rows.
// r1->r2 evidence: SQ_LDS_BANK_CONFLICT 3.49e7 -> 3.47e6 with this padding.
#define STR      20
#define HSTR     (64 * STR)   // u16 per head region

typedef unsigned int       u32;
typedef unsigned short     u16;
typedef unsigned long long u64;
typedef _Float16           f16;

typedef f16    f16x8 __attribute__((ext_vector_type(8)));
typedef f16    f16x4 __attribute__((ext_vector_type(4)));
typedef f16    h2    __attribute__((ext_vector_type(2)));
typedef __fp16 hh2   __attribute__((ext_vector_type(2)));
typedef float  f32x4 __attribute__((ext_vector_type(4)));
union U128h { uint4 u; f16x8 v8; h2 v2[4]; };
union U64h  { uint2 u; f16x4 v4; h2 h[2]; u32 w[2]; u16 s[4]; };

#if __has_builtin(__builtin_amdgcn_exp2f)
  __device__ __forceinline__ float e2(float x) { return __builtin_amdgcn_exp2f(x); }
#else
  __device__ __forceinline__ float e2(float x) { return exp2f(x); }
#endif

__device__ __forceinline__ float fdot2h(h2 a, h2 b, float c) {
#if __has_builtin(__builtin_amdgcn_fdot2)
  return __builtin_amdgcn_fdot2(a, b, c, false);
#else
  return c + (float)a[0] * (float)b[0] + (float)a[1] * (float)b[1];
#endif
}

// pack two fp32 -> 2 fp16 in ONE inst (v_cvt_pkrtz_f16_f32). RTZ; verified
// absmax-neutral in an earlier round.
#if __has_builtin(__builtin_amdgcn_cvt_pkrtz)
__device__ __forceinline__ u32 packh2(float a, float b) {
  hh2 p = __builtin_amdgcn_cvt_pkrtz(a, b);
  return *(u32*)&p;
}
#else
__device__ __forceinline__ u32 packh2(float a, float b) {
  h2 p = {(f16)a, (f16)b};
  return *(u32*)&p;
}
#endif
__device__ __forceinline__ void wb4(u16* __restrict__ dst, f32x4 a) {
  *(uint2*)dst = make_uint2(packh2(a[0], a[1]), packh2(a[2], a[3]));
}

// K=16 MFMA; fall back to zero-padded K=32 (same k-slot semantics).
#if __has_builtin(__builtin_amdgcn_mfma_f32_16x16x16f16)
__device__ __forceinline__ f32x4 mfma16(f16x4 a, f16x4 b, f32x4 c) {
  return __builtin_amdgcn_mfma_f32_16x16x16f16(a, b, c, 0, 0, 0);
}
#elif __has_builtin(__builtin_amdgcn_mfma_f32_16x16x16_f16)
__device__ __forceinline__ f32x4 mfma16(f16x4 a, f16x4 b, f32x4 c) {
  return __builtin_amdgcn_mfma_f32_16x16x16_f16(a, b, c, 0, 0, 0);
}
#else
__device__ __forceinline__ f32x4 mfma16(f16x4 a, f16x4 b, f32x4 c) {
  f16x8 a8 = {a[0], a[1], a[2], a[3], (f16)0, (f16)0, (f16)0, (f16)0};
  f16x8 b8 = {b[0], b[1], b[2], b[3], (f16)0, (f16)0, (f16)0, (f16)0};
  return __builtin_amdgcn_mfma_f32_16x16x32_f16(a8, b8, c, 0, 0, 0);
}
#endif

// LDS: Q/K/V [head][node][STR] f16 (10240 B each) + mask frags (5120 B) +
// double-buffered weight stage (2 x 8192 B). 52224 B -> 3 blocks/CU.
// Rationale (r4): every wave was re-loading the full 8 KB of each weight
// matrix from L2 per layer (~3.3 GB/launch = 41% of chip L2 BW on the SAME
// lines from all CUs). Staging once per block cuts weight traffic 4x and
// converts mmT A-frag loads to conflict-free ds_read_b128.
struct __align__(16) Smem {
  u16 Qh[NHEADS * HSTR];
  u16 Kh[NHEADS * HSTR];
  u16 Vh[NHEADS * HSTR];
  u32 Msk[MSK_U32];
  u16 Wbuf[2][WFRAG];
};  // 52224 B

// ---------------- prep: pack weights in B-fragment order, W_in^T (K zero-padded
// to 32), and attention mask f16-fragments in S^T/P^T tile layout.
extern "C" __global__ void __launch_bounds__(256)
prep_pack(const float* __restrict__ Wq, const float* __restrict__ Wk,
          const float* __restrict__ Wv, const float* __restrict__ Wo,
          const float* __restrict__ W_in, const int* __restrict__ adj,
          u16* __restrict__ wsW) {
  const int w = blockIdx.x;
  if (w < NW) {
    const int l = w >> 2, ty = w & 3;
    const float* src = (ty == 0 ? Wq : ty == 1 ? Wk : ty == 2 ? Wv : Wo) + l * HD * HD;
    const float sc = (ty == 0) ? (0.25f * 1.44269504f) : 1.0f;
    u16* dst = wsW + w * WFRAG;
    for (int f = threadIdx.x; f < 512; f += 256) {
      const int lane = f & 63, kh = (f >> 6) & 1, nt = f >> 7;
      const int n  = nt * 16 + (lane & 15);
      const int k0 = kh * 32 + ((lane >> 4) & 3) * 8;
      u16 tmp[8];
      #pragma unroll
      for (int j = 0; j < 8; ++j) {
        f16 hv = (f16)(src[(k0 + j) * HD + n] * sc);
        tmp[j] = *(u16*)&hv;
      }
      *(uint4*)(dst + f * 8) = *(const uint4*)tmp;
    }
  } else if (w == NW) {
    const int t = threadIdx.x;
    const int mt = t >> 6, lane = t & 63;
    const int mm = lane & 15, qq = (lane >> 4) & 3;
    u16 tmp[8];
    #pragma unroll
    for (int j = 0; j < 8; ++j) {
      const int k = qq * 8 + j;
      f16 hv = (k < FIN) ? (f16)W_in[k * HD + mt * 16 + mm] : (f16)0.0f;
      tmp[j] = *(u16*)&hv;
    }
    *(uint4*)(wsW + NW * WFRAG + t * 8) = *(const uint4*)tmp;
  } else {
    // mask fragments: tile t=(ti,tj) band-ordered; element for lane l, pair pr:
    // i = ti*16 + (l&15), j = tj*16 + ((l>>4)&3)*4 + pr*2 + {0,1}
    static const int TIv[NTILES] = {0, 0, 1, 1, 1, 2, 2, 2, 3, 3};
    static const int TJv[NTILES] = {0, 1, 0, 1, 2, 1, 2, 3, 2, 3};
    u32* wsMsk = (u32*)(wsW + NW * WFRAG + WIN_U16);
    for (int idx = threadIdx.x; idx < MSK_U32; idx += 256) {
      const int tile = idx >> 7, rem = idx & 127;
      const int l = rem >> 1, pr = rem & 1;
      const int i  = TIv[tile] * 16 + (l & 15);
      const int j0 = TJv[tile] * 16 + ((l >> 4) & 3) * 4 + pr * 2;
      const u32 lo = (adj[i * NB + j0]     != 0) ? 0x3C00u : 0u;  // f16 1.0
      const u32 hi = (adj[i * NB + j0 + 1] != 0) ? 0x3C00u : 0u;
      wsMsk[idx] = lo | (hi << 16);
    }
  }
}

// Async-stage one packed 8 KB weight matrix into an LDS buffer.
// Per wave: 2 rounds x 64 lanes x 16 B; LDS dest is wave-uniform base
// (HW adds lane*16), global src carries the matching per-lane offset.
__device__ __forceinline__ void stageW(const u16* __restrict__ src, u16* dst,
                                       int wv, int lane) {
#if __has_builtin(__builtin_amdgcn_global_load_lds)
  #pragma unroll
  for (int r = 0; r < 2; ++r) {
    const u16* g = src + (r * 4 + wv) * 512 + lane * 8;
    u16* d = dst + (r * 4 + wv) * 512;
    __builtin_amdgcn_global_load_lds(
        (const __attribute__((address_space(1))) void*)g,
        (__attribute__((address_space(3))) void*)d, 16, 0, 0);
  }
#else
  #pragma unroll
  for (int r = 0; r < 2; ++r) {
    const uint4 v = *(const uint4*)(src + (r * 4 + wv) * 512 + lane * 8);
    *(uint4*)(dst + (r * 4 + wv) * 512 + lane * 8) = v;
  }
#endif
}

// Transposed GEMM: C^T = W^T @ H^T; A-frags = LDS-staged packed weights,
// B-frags in registers. C^T: feat = mt*16 + q*4 + r, node = wv*16 + (lane&15).
__device__ __forceinline__ void mmT(const u16* wf, U128h b0, U128h b1,
                                    int lane, f32x4 acc[4]) {
  #pragma unroll
  for (int mt = 0; mt < 4; ++mt) {
    U128h a0, a1;
    a0.u = *(const uint4*)(wf + ((mt * 2 + 0) * 64 + lane) * 8);
    a1.u = *(const uint4*)(wf + ((mt * 2 + 1) * 64 + lane) * 8);
    acc[mt] = __builtin_amdgcn_mfma_f32_16x16x32_f16(a0.v8, b0.v8, acc[mt], 0, 0, 0);
    acc[mt] = __builtin_amdgcn_mfma_f32_16x16x32_f16(a1.v8, b1.v8, acc[mt], 0, 0, 0);
  }
}

// Build h B-fragments from hr registers via cross-lane shuffle (no LDS round-trip).
__device__ __forceinline__ void make_bfrags(const float hr[4][4], int q, int m,
                                            U128h& b0, U128h& b1) {
  u32 p[8];
  #pragma unroll
  for (int mt = 0; mt < 4; ++mt) {
    p[2 * mt]     = packh2(hr[mt][0], hr[mt][1]);
    p[2 * mt + 1] = packh2(hr[mt][2], hr[mt][3]);
  }
  const int sA = (2 * (q & 1)) * 16 + m;
  const int sB = sA + 16;
  u32 A[8], B[8];
  #pragma unroll
  for (int k = 0; k < 8; ++k) A[k] = (u32)__shfl((int)p[k], sA, 64);
  #pragma unroll
  for (int k = 0; k < 8; ++k) B[k] = (u32)__shfl((int)p[k], sB, 64);
  const bool hi = (q & 2) != 0;
  b0.u.x = hi ? A[2] : A[0];  b0.u.y = hi ? A[3] : A[1];
  b0.u.z = hi ? B[2] : B[0];  b0.u.w = hi ? B[3] : B[1];
  b1.u.x = hi ? A[6] : A[4];  b1.u.y = hi ? A[7] : A[5];
  b1.u.z = hi ? B[6] : B[4];  b1.u.w = hi ? B[7] : B[5];
}

extern "C" __global__ void __launch_bounds__(NTH, 3)
gnn_fused(const float* __restrict__ x, const float* __restrict__ b_in,
          const u16* __restrict__ wsW, const float* __restrict__ bo,
          const float* __restrict__ ln_g, const float* __restrict__ ln_b,
          const float* __restrict__ Wp1, const float* __restrict__ bp1,
          const float* __restrict__ Wp2, const float* __restrict__ bp2,
          float* __restrict__ out) {
  __shared__ Smem s;
  const int t    = threadIdx.x;
  const int lane = t & 63;
  const int wv   = t >> 6;
  const int eg   = (int)blockIdx.x;
  const int m    = lane & 15, q = lane >> 4;
  const int node = wv * 16 + m;

  const u16* wsWin = wsW + NW * WFRAG;

  // ---------------- phase 0: zero + stage x as f16 [node][32] in Kh region;
  // copy mask frags into LDS; async-stage Wq(layer 0) into Wbuf[0].
  ((uint4*)s.Kh)[t] = make_uint4(0u, 0u, 0u, 0u);   // 4096 B staging region
  {
    const uint4* mg4 = (const uint4*)(wsWin + WIN_U16);
    ((uint4*)s.Msk)[t] = mg4[t];
    if (t < 64) ((uint4*)s.Msk)[256 + t] = mg4[256 + t];
  }
  __syncthreads();
  if (t < (NB * FIN) / 4) {
    const int nd = t / 3, pos = (t % 3) * 4;
    const float4 v4 = *(const float4*)(x + eg * NB * FIN + t * 4);
    *(uint2*)&s.Kh[nd * 32 + pos] = make_uint2(packh2(v4.x, v4.y), packh2(v4.z, v4.w));
  }
  stageW(wsW + 0 * WFRAG, s.Wbuf[0], wv, lane);   // Wq(0) -> buf0 (async)
  __syncthreads();

  // ---------------- input projection via MFMA: h^T = W_in^T @ x^T (K=32 padded)
  float hr[4][4];   // hr[mt][r]: h[node][feat = mt*16 + q*4 + r]
  {
    U128h xb;
    xb.u = *(const uint4*)&s.Kh[node * 32 + q * 8];
    #pragma unroll
    for (int mt = 0; mt < 4; ++mt) {
      U128h a0;
      a0.u = *(const uint4*)(wsWin + (mt * 64 + lane) * 8);
      f32x4 acc = {0.f, 0.f, 0.f, 0.f};
      acc = __builtin_amdgcn_mfma_f32_16x16x32_f16(a0.v8, xb.v8, acc, 0, 0, 0);
      const f32x4 b4 = *(const f32x4*)&b_in[mt * 16 + q * 4];
      #pragma unroll
      for (int r = 0; r < 4; ++r) hr[mt][r] = acc[r] + b4[r];
    }
  }
  __syncthreads();   // x staging dead (Kh free for k); Wq(0) stage drained

  // ---------------- transformer layers
  // Weight pipeline (double buffer): Wq->buf0, Wk->buf1, Wv->buf0, Wo->buf1,
  // Wq(l+1)->buf0. Each stage is issued one compute phase ahead; the barrier
  // at the end of that phase drains it. Overwrite hazards: the buffer being
  // staged was last READ before a barrier that precedes the stage issue.
  for (int l = 0; l < NLAYERS; ++l) {
    const u16* wl = wsW + (l * 4) * WFRAG;

    // h B-fragments from registers (shuffle transpose), then fused q/k/v
    {
      U128h b0, b1;
      make_bfrags(hr, q, m, b0, b1);

      stageW(wl + 1 * WFRAG, s.Wbuf[1], wv, lane);   // Wk -> buf1 (async)
      f32x4 aq[4] = {{0,0,0,0},{0,0,0,0},{0,0,0,0},{0,0,0,0}};
      mmT(s.Wbuf[0], b0, b1, lane, aq);              // Wq from buf0
      #pragma unroll
      for (int mt = 0; mt < 4; ++mt)
        wb4(&s.Qh[mt * HSTR + node * STR + q * 4], aq[mt]);
      __syncthreads();                               // Wk staged; buf0 reads done

      stageW(wl + 2 * WFRAG, s.Wbuf[0], wv, lane);   // Wv -> buf0 (async)
      f32x4 ak[4] = {{0,0,0,0},{0,0,0,0},{0,0,0,0},{0,0,0,0}};
      mmT(s.Wbuf[1], b0, b1, lane, ak);              // Wk from buf1
      #pragma unroll
      for (int mt = 0; mt < 4; ++mt)
        wb4(&s.Kh[mt * HSTR + node * STR + q * 4], ak[mt]);
      __syncthreads();                               // Wv staged; buf1 reads done

      stageW(wl + 3 * WFRAG, s.Wbuf[1], wv, lane);   // Wo -> buf1 (async)
      f32x4 av[4] = {{0,0,0,0},{0,0,0,0},{0,0,0,0},{0,0,0,0}};
      mmT(s.Wbuf[0], b0, b1, lane, av);              // Wv from buf0
      #pragma unroll
      for (int mt = 0; mt < 4; ++mt)
        wb4(&s.Vh[mt * HSTR + node * STR + q * 4], av[mt]);
    }
    __syncthreads();   // QKV visible; Wo staged

    // ---- dense band-tile MFMA attention: wave = head hh.
    // S^T = K·Q^T (A=K-frag, B=Q-frag); S^T C-layout == P^T B-frag layout for
    // O^T = V^T·P^T. Mask as f16 0/1 pk_mul on packed P (LDS); denom via
    // fdot2+shfl.
    {
      const int hh = wv;
      const u16* Qp = s.Qh + hh * HSTR;
      const u16* Kp = s.Kh + hh * HSTR;
      const u16* Vp = s.Vh + hh * HSTR;
      u16*       Op = s.Qh + hh * HSTR;   // O overwrites own Q region (safe)
      const h2 one2 = {(f16)1.0f, (f16)1.0f};
      const f32x4 z4 = {0.f, 0.f, 0.f, 0.f};

      f16x4 kf[4], vf[4];
      #pragma unroll
      for (int tj = 0; tj < 4; ++tj) {
        U64h tk; tk.u = *(const uint2*)&Kp[(tj * 16 + m) * STR + q * 4];
        kf[tj] = tk.v4;
      }
      #pragma unroll
      for (int kt = 0; kt < 4; ++kt) {
        const int j0 = kt * 16 + q * 4;   // V^T A-frag: strided u16 gather
        U64h tv;
        tv.s[0] = Vp[(j0 + 0) * STR + m];
        tv.s[1] = Vp[(j0 + 1) * STR + m];
        tv.s[2] = Vp[(j0 + 2) * STR + m];
        tv.s[3] = Vp[(j0 + 3) * STR + m];
        vf[kt] = tv.v4;
      }

#define ATTN_TI(TI, TJ0, NTJ, T0)                                              \
      {                                                                        \
        U64h tq; tq.u = *(const uint2*)&Qp[((TI) * 16 + m) * STR + q * 4];     \
        const f16x4 qf = tq.v4;                                                \
        f32x4 ot = z4;                                                         \
        float dsum = 0.0f;                                                     \
        _Pragma("unroll")                                                      \
        for (int dt = 0; dt < (NTJ); ++dt) {                                   \
          const int tj = (TJ0) + dt;                                           \
          f32x4 st = mfma16(kf[tj], qf, z4);                                   \
          const uint2 mmv = *(const uint2*)&s.Msk[((T0) + dt) * 128 + (lane << 1)]; \
          U64h pp;                                                             \
          pp.w[0] = packh2(e2(st[0]), e2(st[1]));                              \
          pp.w[1] = packh2(e2(st[2]), e2(st[3]));                              \
          pp.h[0] *= *(const h2*)&mmv.x;                                       \
          pp.h[1] *= *(const h2*)&mmv.y;                                       \
          dsum = fdot2h(pp.h[0], one2, dsum);                                  \
          dsum = fdot2h(pp.h[1], one2, dsum);                                  \
          ot = mfma16(vf[tj], pp.v4, ot);                                      \
        }                                                                      \
        dsum += __shfl_xor(dsum, 16, 64);                                      \
        dsum += __shfl_xor(dsum, 32, 64);                                      \
        const float rinv = 1.0f / dsum;                                        \
        ot[0] *= rinv; ot[1] *= rinv; ot[2] *= rinv; ot[3] *= rinv;            \
        wb4(&Op[((TI) * 16 + m) * STR + q * 4], ot);                           \
      }

      ATTN_TI(0, 0, 2, 0)
      ATTN_TI(1, 0, 3, 2)
      ATTN_TI(2, 1, 3, 5)
      ATTN_TI(3, 2, 2, 8)
#undef ATTN_TI
    }
    __syncthreads();   // O visible

    // u = h + o @ Wo + bo (transposed GEMM, o B-frags from [head][node][STR]),
    // LN over q-lanes. Stage next layer's Wq under this phase.
    {
      if (l + 1 < NLAYERS)
        stageW(wsW + ((l + 1) * 4) * WFRAG, s.Wbuf[0], wv, lane);  // Wq' -> buf0

      const int hq = q >> 1, dof = (q & 1) * 8;
      const u16* ob0 = &s.Qh[hq * HSTR + node * STR + dof];
      const u16* ob1 = &s.Qh[(2 + hq) * HSTR + node * STR + dof];
      U128h b0, b1;
      const uint2 x0 = *(const uint2*)ob0, x1 = *(const uint2*)(ob0 + 4);
      const uint2 y0 = *(const uint2*)ob1, y1v = *(const uint2*)(ob1 + 4);
      b0.u = make_uint4(x0.x, x0.y, x1.x, x1.y);
      b1.u = make_uint4(y0.x, y0.y, y1v.x, y1v.y);
      f32x4 ao[4] = {{0,0,0,0},{0,0,0,0},{0,0,0,0},{0,0,0,0}};
      mmT(s.Wbuf[1], b0, b1, lane, ao);              // Wo from buf1

      float uu[4][4];
      float s1 = 0.0f, s2 = 0.0f;
      #pragma unroll
      for (int mt = 0; mt < 4; ++mt) {
        const f32x4 bo4 = *(const f32x4*)&bo[l * HD + mt * 16 + q * 4];
        #pragma unroll
        for (int r = 0; r < 4; ++r) {
          const float v = hr[mt][r] + ao[mt][r] + bo4[r];
          uu[mt][r] = v;
          s1 += v;
          s2 += v * v;
        }
      }
      s1 += __shfl_xor(s1, 16, 64); s1 += __shfl_xor(s1, 32, 64);
      s2 += __shfl_xor(s2, 16, 64); s2 += __shfl_xor(s2, 32, 64);
      const float mu  = s1 * (1.0f / 64.0f);
      const float var = s2 * (1.0f / 64.0f) - mu * mu;
      const float rs  = rsqrtf(var + LN_EPS);
      #pragma unroll
      for (int mt = 0; mt < 4; ++mt) {
        const f32x4 g4 = *(const f32x4*)&ln_g[l * HD + mt * 16 + q * 4];
        const f32x4 b4 = *(const f32x4*)&ln_b[l * HD + mt * 16 + q * 4];
        #pragma unroll
        for (int r = 0; r < 4; ++r)
          hr[mt][r] = (uu[mt][r] - mu) * rs * g4[r] + b4[r];
      }
    }
    if (l + 1 < NLAYERS) __syncthreads();   // protect o reads; drain Wq' stage
  }

  // ---------------- head: butterfly over node-lanes, pool in Kh alias, MLP
  float* pool = (float*)s.Kh;   // Kh dead (last read: layer-2 attention, barrier'd)
  float* y1   = pool + HD;
  __syncthreads();
  if (t < HD) pool[t] = 0.0f;
  __syncthreads();
  {
    #pragma unroll
    for (int mt = 0; mt < 4; ++mt)
      #pragma unroll
      for (int r = 0; r < 4; ++r) {
        float v = hr[mt][r];
        v += __shfl_xor(v, 1, 64); v += __shfl_xor(v, 2, 64);
        v += __shfl_xor(v, 4, 64); v += __shfl_xor(v, 8, 64);
        hr[mt][r] = v;
      }
    if (m == 0) {
      #pragma unroll
      for (int mt = 0; mt < 4; ++mt)
        #pragma unroll
        for (int r = 0; r < 4; ++r)
          atomicAdd(&pool[mt * 16 + q * 4 + r], hr[mt][r] * (1.0f / 64.0f));
    }
  }
  __syncthreads();
  if (t < HD) {
    float acc = bp1[t];
    #pragma unroll 8
    for (int k = 0; k < HD; ++k) acc = fmaf(pool[k], Wp1[k * HD + t], acc);
    y1[t] = fmaxf(acc, 0.0f);
  }
  __syncthreads();
  if (t < ODIM) {
    float acc = bp2[t];
    #pragma unroll 8
    for (int c = 0; c < HD; ++c) acc = fmaf(y1[c], Wp2[c * ODIM + t], acc);
    out[eg * ODIM + t] = acc;
  }
}

extern "C" void kernel_launch(void* const* d_in, const int* in_sizes, int n_in,
                              void* d_out, int out_size, void* d_ws, size_t ws_size,
                              hipStream_t stream) {
  const float* x    = (const float*)d_in[0];
  const int*   adj  = (const int*)d_in[1];
  const float* W_in = (const float*)d_in[2];
  const float* b_in = (const float*)d_in[3];
  const float* Wq   = (const float*)d_in[4];
  const float* Wk   = (const float*)d_in[5];
  const float* Wv   = (const float*)d_in[6];
  const float* Wo   = (const float*)d_in[7];
  const float* bo   = (const float*)d_in[8];
  const float* lng  = (const float*)d_in[9];
  const float* lnb  = (const float*)d_in[10];
  const float* Wp1  = (const float*)d_in[11];
  const float* bp1  = (const float*)d_in[12];
  const float* Wp2  = (const float*)d_in[13];
  const float* bp2  = (const float*)d_in[14];
  float* outp = (float*)d_out;
  u16*   wsW  = (u16*)d_ws;   // 12*4096 + 2048 u16 + 5120 B mask frags = ~105 KB

  hipLaunchKernelGGL(prep_pack, dim3(NW + 2), dim3(256), 0, stream,
                     Wq, Wk, Wv, Wo, W_in, adj, wsW);
  hipLaunchKernelGGL(gnn_fused, dim3(BTOT), dim3(NTH), 0, stream,
                     x, b_in, wsW, bo, lng, lnb, Wp1, bp1, Wp2, bp2, outp);
}

// Round 7
// 251.197 us; speedup vs baseline: 1.1703x; 1.1703x over previous
//
#include <hip/hip_runtime.h>
#include <stdint.h>

// Problem constants
#define NB       64
#define FIN      12
#define HD       64
#define NHEADS   4
#define DHEAD    16
#define NLAYERS  3
#define ODIM     128
#define LN_EPS   1e-5f
#define BTOT     8192

#define NTH      256   // 4 independent waves per block; ONE WAVE = ONE GRAPH
#define NWAVE    4
#define NW       (NLAYERS * 4)
#define WFRAG    4096  // u16 per packed weight
#define WIN_U16  2048  // packed W_in^T (zero-padded K=32)
#define NTILES   10    // band tiles (|tj-ti|<=1) of the 4x4 tile grid
#define MSK_U32  (NTILES * 64 * 2)   // 1280 u32 of f16 0/1 fragment masks

typedef unsigned int       u32;
typedef unsigned short     u16;
typedef unsigned long long u64;
typedef _Float16           f16;

typedef f16    f16x8 __attribute__((ext_vector_type(8)));
typedef f16    f16x4 __attribute__((ext_vector_type(4)));
typedef f16    h2    __attribute__((ext_vector_type(2)));
typedef __fp16 hh2   __attribute__((ext_vector_type(2)));
typedef float  f32x4 __attribute__((ext_vector_type(4)));
union U128h { uint4 u; f16x8 v8; f16x4 v4h[2]; h2 v2[4]; };
union U64h  { uint2 u; f16x4 v4; h2 h[2]; u32 w[2]; u16 s[4]; };

#if __has_builtin(__builtin_amdgcn_exp2f)
  __device__ __forceinline__ float e2(float x) { return __builtin_amdgcn_exp2f(x); }
#else
  __device__ __forceinline__ float e2(float x) { return exp2f(x); }
#endif

__device__ __forceinline__ float fdot2h(h2 a, h2 b, float c) {
#if __has_builtin(__builtin_amdgcn_fdot2)
  return __builtin_amdgcn_fdot2(a, b, c, false);
#else
  return c + (float)a[0] * (float)b[0] + (float)a[1] * (float)b[1];
#endif
}

#if __has_builtin(__builtin_amdgcn_cvt_pkrtz)
__device__ __forceinline__ u32 packh2(float a, float b) {
  hh2 p = __builtin_amdgcn_cvt_pkrtz(a, b);
  return *(u32*)&p;
}
#else
__device__ __forceinline__ u32 packh2(float a, float b) {
  h2 p = {(f16)a, (f16)b};
  return *(u32*)&p;
}
#endif

#if __has_builtin(__builtin_amdgcn_mfma_f32_16x16x16f16)
__device__ __forceinline__ f32x4 mfma16(f16x4 a, f16x4 b, f32x4 c) {
  return __builtin_amdgcn_mfma_f32_16x16x16f16(a, b, c, 0, 0, 0);
}
#elif __has_builtin(__builtin_amdgcn_mfma_f32_16x16x16_f16)
__device__ __forceinline__ f32x4 mfma16(f16x4 a, f16x4 b, f32x4 c) {
  return __builtin_amdgcn_mfma_f32_16x16x16_f16(a, b, c, 0, 0, 0);
}
#else
__device__ __forceinline__ f32x4 mfma16(f16x4 a, f16x4 b, f32x4 c) {
  f16x8 a8 = {a[0], a[1], a[2], a[3], (f16)0, (f16)0, (f16)0, (f16)0};
  f16x8 b8 = {b[0], b[1], b[2], b[3], (f16)0, (f16)0, (f16)0, (f16)0};
  return __builtin_amdgcn_mfma_f32_16x16x32_f16(a8, b8, c, 0, 0, 0);
}
#endif

__device__ __forceinline__ f32x4 mfma32(f16x8 a, f16x8 b, f32x4 c) {
  return __builtin_amdgcn_mfma_f32_16x16x32_f16(a, b, c, 0, 0, 0);
}

__device__ __forceinline__ f16x4 pa4(u32 w0, u32 w1) {
  U64h u; u.w[0] = w0; u.w[1] = w1; return u.v4;
}

// NO activation LDS. Masks (block-shared, read-only) + per-wave MLP scratch.
struct __align__(16) Smem {
  u32   Msk[MSK_U32];        // 5120 B
  float scr[NWAVE][128];     // per-wave: pooled[64] + y1[64]
};  // 7168 B

// ---------------- prep: Wq/Wk/Wo packed in mmT B-fragment order (Wq carries
// softmax scale*log2e); Wv packed for the DIRECT orientation (V = H @ Wv) so
// the PV V^T A-fragment falls out of the GEMM with zero shuffles; W_in^T
// (K zero-padded to 32); adjacency as f16 0/1 fragment masks.
extern "C" __global__ void __launch_bounds__(256)
prep_pack(const float* __restrict__ Wq, const float* __restrict__ Wk,
          const float* __restrict__ Wv, const float* __restrict__ Wo,
          const float* __restrict__ W_in, const int* __restrict__ adj,
          u16* __restrict__ wsW) {
  const int w = blockIdx.x;
  if (w < NW) {
    const int l = w >> 2, ty = w & 3;
    u16* dst = wsW + w * WFRAG;
    if (ty == 2) {
      // direct-orientation Wv: frag fi = dt*2+c; elem e: kk = c*2+(e>>2), j=e&3
      // value = Wv[kk*16 + q*4 + j][dt*16 + m]  (B-frag lane (m,q))
      const float* src = Wv + l * HD * HD;
      for (int f = threadIdx.x; f < 512; f += 256) {
        const int lane = f & 63, fi = f >> 6;
        const int dt = fi >> 1, c = fi & 1;
        const int mm = lane & 15, mq = (lane >> 4) & 3;
        u16 tmp[8];
        #pragma unroll
        for (int e = 0; e < 8; ++e) {
          const int kk = c * 2 + (e >> 2), j = e & 3;
          f16 hv = (f16)src[(kk * 16 + mq * 4 + j) * HD + dt * 16 + mm];
          tmp[e] = *(u16*)&hv;
        }
        *(uint4*)(dst + f * 8) = *(const uint4*)tmp;
      }
    } else {
      const float* src = (ty == 0 ? Wq : ty == 1 ? Wk : Wo) + l * HD * HD;
      const float sc = (ty == 0) ? (0.25f * 1.44269504f) : 1.0f;
      for (int f = threadIdx.x; f < 512; f += 256) {
        const int lane = f & 63, kh = (f >> 6) & 1, nt = f >> 7;
        const int n  = nt * 16 + (lane & 15);
        const int k0 = kh * 32 + ((lane >> 4) & 3) * 8;
        u16 tmp[8];
        #pragma unroll
        for (int j = 0; j < 8; ++j) {
          f16 hv = (f16)(src[(k0 + j) * HD + n] * sc);
          tmp[j] = *(u16*)&hv;
        }
        *(uint4*)(dst + f * 8) = *(const uint4*)tmp;
      }
    }
  } else if (w == NW) {
    const int t = threadIdx.x;
    const int mt = t >> 6, lane = t & 63;
    const int mm = lane & 15, qq = (lane >> 4) & 3;
    u16 tmp[8];
    #pragma unroll
    for (int j = 0; j < 8; ++j) {
      const int k = qq * 8 + j;
      f16 hv = (k < FIN) ? (f16)W_in[k * HD + mt * 16 + mm] : (f16)0.0f;
      tmp[j] = *(u16*)&hv;
    }
    *(uint4*)(wsW + NW * WFRAG + t * 8) = *(const uint4*)tmp;
  } else {
    static const int TIv[NTILES] = {0, 0, 1, 1, 1, 2, 2, 2, 3, 3};
    static const int TJv[NTILES] = {0, 1, 0, 1, 2, 1, 2, 3, 2, 3};
    u32* wsMsk = (u32*)(wsW + NW * WFRAG + WIN_U16);
    for (int idx = threadIdx.x; idx < MSK_U32; idx += 256) {
      const int tile = idx >> 7, rem = idx & 127;
      const int l = rem >> 1, pr = rem & 1;
      const int i  = TIv[tile] * 16 + (l & 15);
      const int j0 = TJv[tile] * 16 + ((l >> 4) & 3) * 4 + pr * 2;
      const u32 lo = (adj[i * NB + j0]     != 0) ? 0x3C00u : 0u;
      const u32 hi = (adj[i * NB + j0 + 1] != 0) ? 0x3C00u : 0u;
      wsMsk[idx] = lo | (hi << 16);
    }
  }
}

// B-fragment builder from 8 pre-packed h2 words (p[2*mt+c] = feats mt*16+q*4+
// {2c,2c+1} of the lane's node). Verified shuffle-transpose (4 rounds in prod).
__device__ __forceinline__ void mb_from_p(const u32 p[8], int q, int m,
                                          U128h& b0, U128h& b1) {
  const int sA = (2 * (q & 1)) * 16 + m;
  const int sB = sA + 16;
  u32 A[8], B[8];
  #pragma unroll
  for (int k = 0; k < 8; ++k) A[k] = (u32)__shfl((int)p[k], sA, 64);
  #pragma unroll
  for (int k = 0; k < 8; ++k) B[k] = (u32)__shfl((int)p[k], sB, 64);
  const bool hi = (q & 2) != 0;
  b0.u.x = hi ? A[2] : A[0];  b0.u.y = hi ? A[3] : A[1];
  b0.u.z = hi ? B[2] : B[0];  b0.u.w = hi ? B[3] : B[1];
  b1.u.x = hi ? A[6] : A[4];  b1.u.y = hi ? A[7] : A[5];
  b1.u.z = hi ? B[6] : B[4];  b1.u.w = hi ? B[7] : B[5];
}

extern "C" __global__ void __launch_bounds__(NTH, 2)
gnn_fused(const float* __restrict__ x, const float* __restrict__ b_in,
          const u16* __restrict__ wsW, const float* __restrict__ bo,
          const float* __restrict__ ln_g, const float* __restrict__ ln_b,
          const float* __restrict__ Wp1, const float* __restrict__ bp1,
          const float* __restrict__ Wp2, const float* __restrict__ bp2,
          float* __restrict__ out) {
  __shared__ Smem s;
  const int tb = threadIdx.x;
  const int t  = tb & 63;                // lane within wave
  const int wv = tb >> 6;                // wave id
  const int m  = t & 15, q = t >> 4;
  const int g  = (int)blockIdx.x * NWAVE + wv;   // graph id (one per wave)

  const u16* wsWin = wsW + NW * WFRAG;

  // stage masks (block-shared, layer/head/graph-invariant); sole block barrier
  {
    const uint4* mg4 = (const uint4*)(wsWin + WIN_U16);
    if (tb < 256) ((uint4*)s.Msk)[tb] = mg4[tb];
    if (tb < 64)  ((uint4*)s.Msk)[256 + tb] = mg4[256 + tb];
  }
  __syncthreads();

  // ---------------- input projection: h^T = W_in^T @ x^T (K=32 padded),
  // x B-frags built straight from global (lane (m,q) supplies feats q*8+j).
  f32x4 hr[4][4];   // hr[ng][mt]: h[node = ng*16+m][feat = mt*16 + q*4 + r]
  {
    #pragma unroll
    for (int ng = 0; ng < 4; ++ng) {
      U128h xb;
      xb.u = make_uint4(0u, 0u, 0u, 0u);
      const float* gx = x + (size_t)(g * NB + ng * 16 + m) * FIN;
      if (q == 0) {
        const float4 fa = *(const float4*)gx;
        const float4 fb = *(const float4*)(gx + 4);
        xb.u = make_uint4(packh2(fa.x, fa.y), packh2(fa.z, fa.w),
                          packh2(fb.x, fb.y), packh2(fb.z, fb.w));
      } else if (q == 1) {
        const float4 fc = *(const float4*)(gx + 8);
        xb.u.x = packh2(fc.x, fc.y);
        xb.u.y = packh2(fc.z, fc.w);
      }
      #pragma unroll
      for (int mt = 0; mt < 4; ++mt) {
        U128h aw;
        aw.u = *(const uint4*)(wsWin + (mt * 64 + t) * 8);
        f32x4 acc = {0.f, 0.f, 0.f, 0.f};
        acc = mfma32(aw.v8, xb.v8, acc);
        const f32x4 b4 = *(const f32x4*)&b_in[mt * 16 + q * 4];
        hr[ng][mt] = acc + b4;
      }
    }
  }

  // ---------------- transformer layers: wave-autonomous, NO barriers,
  // NO activation LDS. Loop kept rolled to bound codegen size.
  #pragma unroll 1
  for (int l = 0; l < NLAYERS; ++l) {
    const u16* wq  = wsW + (l * 4 + 0) * WFRAG;
    const u16* wk  = wsW + (l * 4 + 1) * WFRAG;
    const u16* wvd = wsW + (l * 4 + 2) * WFRAG;
    const u16* wo  = wsW + (l * 4 + 3) * WFRAG;
    const f32x4 z4 = {0.f, 0.f, 0.f, 0.f};

    // packed h words: hp[ng][2*mt+c] = f16x2(hr[ng][mt][2c], [2c+1]).
    // Doubles as the V-GEMM A-fragment.
    u32 hp[4][8];
    #pragma unroll
    for (int ng = 0; ng < 4; ++ng)
      #pragma unroll
      for (int mt = 0; mt < 4; ++mt) {
        hp[ng][2 * mt]     = packh2(hr[ng][mt][0], hr[ng][mt][1]);
        hp[ng][2 * mt + 1] = packh2(hr[ng][mt][2], hr[ng][mt][3]);
      }

    // V = H @ Wv (direct)  ->  vf[hh][kt] = V[kt*16+q*4+j][hh*16+m]
    // = exactly the V^T A-fragment PV needs: zero-shuffle V transpose.
    U64h vf[4][4];
    #pragma unroll
    for (int dt = 0; dt < 4; ++dt) {
      U128h bv0, bv1;
      bv0.u = *(const uint4*)(wvd + ((dt * 2 + 0) * 64 + t) * 8);
      bv1.u = *(const uint4*)(wvd + ((dt * 2 + 1) * 64 + t) * 8);
      #pragma unroll
      for (int nt = 0; nt < 4; ++nt) {
        f32x4 acc = z4;
        acc = mfma16(pa4(hp[nt][0], hp[nt][1]), bv0.v4h[0], acc);
        acc = mfma16(pa4(hp[nt][2], hp[nt][3]), bv0.v4h[1], acc);
        acc = mfma16(pa4(hp[nt][4], hp[nt][5]), bv1.v4h[0], acc);
        acc = mfma16(pa4(hp[nt][6], hp[nt][7]), bv1.v4h[1], acc);
        vf[dt][nt].w[0] = packh2(acc[0], acc[1]);
        vf[dt][nt].w[1] = packh2(acc[2], acc[3]);
      }
    }

    // h B-fragments (shuffle transpose); hp dead after this.
    U128h hb[4][2];
    #pragma unroll
    for (int ng = 0; ng < 4; ++ng) mb_from_p(hp[ng], q, m, hb[ng][0], hb[ng][1]);

    // Q^T = Wq^T @ H^T  ->  qf[hh][ti] = Q[ti*16+m][hh*16+q*4+j]
    U64h qf[4][4];
    #pragma unroll
    for (int mt = 0; mt < 4; ++mt) {
      U128h a0, a1;
      a0.u = *(const uint4*)(wq + ((mt * 2 + 0) * 64 + t) * 8);
      a1.u = *(const uint4*)(wq + ((mt * 2 + 1) * 64 + t) * 8);
      #pragma unroll
      for (int ng = 0; ng < 4; ++ng) {
        f32x4 acc = z4;
        acc = mfma32(a0.v8, hb[ng][0].v8, acc);
        acc = mfma32(a1.v8, hb[ng][1].v8, acc);
        qf[mt][ng].w[0] = packh2(acc[0], acc[1]);
        qf[mt][ng].w[1] = packh2(acc[2], acc[3]);
      }
    }
    // K^T = Wk^T @ H^T  ->  kf[hh][tj] = K[tj*16+m][hh*16+q*4+j]; hb dead after.
    U64h kf[4][4];
    #pragma unroll
    for (int mt = 0; mt < 4; ++mt) {
      U128h a0, a1;
      a0.u = *(const uint4*)(wk + ((mt * 2 + 0) * 64 + t) * 8);
      a1.u = *(const uint4*)(wk + ((mt * 2 + 1) * 64 + t) * 8);
      #pragma unroll
      for (int ng = 0; ng < 4; ++ng) {
        f32x4 acc = z4;
        acc = mfma32(a0.v8, hb[ng][0].v8, acc);
        acc = mfma32(a1.v8, hb[ng][1].v8, acc);
        kf[mt][ng].w[0] = packh2(acc[0], acc[1]);
        kf[mt][ng].w[1] = packh2(acc[2], acc[3]);
      }
    }

    // ---- band-tile attention, all 4 heads in-wave.
    // S^T = K·Q^T ; P masked via f16 0/1 frags; O^T = V^T·P^T.
    // O lands node<->m (same as h); rinv folded into the f16 pack (opk).
    u32 opk[4][8];   // opk[ti][2*hh+c]: packed O, ready for mb_from_p
    {
      const h2 one2 = {(f16)1.0f, (f16)1.0f};
#define ATTN_HT(HH, TI, TJ0, NTJ, T0)                                          \
      {                                                                        \
        f32x4 ot = z4;                                                         \
        float dsum = 0.0f;                                                     \
        _Pragma("unroll")                                                      \
        for (int dt = 0; dt < (NTJ); ++dt) {                                   \
          const int tj = (TJ0) + dt;                                           \
          f32x4 st = mfma16(kf[HH][tj].v4, qf[HH][TI].v4, z4);                 \
          const uint2 mmv = *(const uint2*)&s.Msk[((T0) + dt) * 128 + (t << 1)]; \
          U64h pp;                                                             \
          pp.w[0] = packh2(e2(st[0]), e2(st[1]));                              \
          pp.w[1] = packh2(e2(st[2]), e2(st[3]));                              \
          pp.h[0] *= *(const h2*)&mmv.x;                                       \
          pp.h[1] *= *(const h2*)&mmv.y;                                       \
          dsum = fdot2h(pp.h[0], one2, dsum);                                  \
          dsum = fdot2h(pp.h[1], one2, dsum);                                  \
          ot = mfma16(vf[HH][tj].v4, pp.v4, ot);                               \
        }                                                                      \
        dsum += __shfl_xor(dsum, 16, 64);                                      \
        dsum += __shfl_xor(dsum, 32, 64);                                      \
        const float rinv = 1.0f / dsum;                                        \
        opk[TI][2 * (HH)]     = packh2(ot[0] * rinv, ot[1] * rinv);            \
        opk[TI][2 * (HH) + 1] = packh2(ot[2] * rinv, ot[3] * rinv);            \
      }
      #pragma unroll
      for (int hh = 0; hh < 4; ++hh) {
        ATTN_HT(hh, 0, 0, 2, 0)
        ATTN_HT(hh, 1, 0, 3, 2)
        ATTN_HT(hh, 2, 1, 3, 5)
        ATTN_HT(hh, 3, 2, 2, 8)
      }
#undef ATTN_HT
    }

    // u^T = Wo^T @ O^T + h + bo ; LN over feats (q-lane reduce). O B-frags via
    // the same verified mb_from_p (opk has identical register form to hp).
    {
      U128h a[8];
      #pragma unroll
      for (int i = 0; i < 8; ++i) a[i].u = *(const uint4*)(wo + (i * 64 + t) * 8);
      #pragma unroll
      for (int ng = 0; ng < 4; ++ng) {
        U128h ob0, ob1;
        mb_from_p(opk[ng], q, m, ob0, ob1);
        float s1 = 0.0f, s2 = 0.0f;
        #pragma unroll
        for (int mt = 0; mt < 4; ++mt) {
          f32x4 acc = z4;
          acc = mfma32(a[mt * 2].v8,     ob0.v8, acc);
          acc = mfma32(a[mt * 2 + 1].v8, ob1.v8, acc);
          const f32x4 bo4 = *(const f32x4*)&bo[l * HD + mt * 16 + q * 4];
          const f32x4 u4 = hr[ng][mt] + acc + bo4;
          hr[ng][mt] = u4;
          #pragma unroll
          for (int r = 0; r < 4; ++r) { s1 += u4[r]; s2 += u4[r] * u4[r]; }
        }
        s1 += __shfl_xor(s1, 16, 64); s1 += __shfl_xor(s1, 32, 64);
        s2 += __shfl_xor(s2, 16, 64); s2 += __shfl_xor(s2, 32, 64);
        const float mu  = s1 * (1.0f / 64.0f);
        const float var = s2 * (1.0f / 64.0f) - mu * mu;
        const float rs  = rsqrtf(var + LN_EPS);
        #pragma unroll
        for (int mt = 0; mt < 4; ++mt) {
          const f32x4 g4  = *(const f32x4*)&ln_g[l * HD + mt * 16 + q * 4];
          const f32x4 be4 = *(const f32x4*)&ln_b[l * HD + mt * 16 + q * 4];
          #pragma unroll
          for (int r = 0; r < 4; ++r)
            hr[ng][mt][r] = (hr[ng][mt][r] - mu) * rs * g4[r] + be4[r];
        }
      }
    }
  }

  // ---------------- head: pool (in-lane ng-sum + m-lane butterfly), MLP via
  // per-wave 512 B scratch. All wave-internal: program order, no barriers.
  {
    #pragma unroll
    for (int mt = 0; mt < 4; ++mt) {
      f32x4 v = hr[0][mt] + hr[1][mt] + hr[2][mt] + hr[3][mt];
      #pragma unroll
      for (int r = 0; r < 4; ++r) {
        float vv = v[r];
        vv += __shfl_xor(vv, 1, 64); vv += __shfl_xor(vv, 2, 64);
        vv += __shfl_xor(vv, 4, 64); vv += __shfl_xor(vv, 8, 64);
        v[r] = vv * (1.0f / 64.0f);
      }
      if (m == 0) *(f32x4*)&s.scr[wv][mt * 16 + q * 4] = v;
    }
  }
  {
    float acc = bp1[t];
    #pragma unroll 8
    for (int k = 0; k < HD; ++k) acc = fmaf(s.scr[wv][k], Wp1[k * HD + t], acc);
    s.scr[wv][64 + t] = fmaxf(acc, 0.0f);
  }
  {
    float a0 = bp2[t], a1 = bp2[t + 64];
    #pragma unroll 8
    for (int c = 0; c < HD; ++c) {
      const float yc = s.scr[wv][64 + c];
      a0 = fmaf(yc, Wp2[c * ODIM + t], a0);
      a1 = fmaf(yc, Wp2[c * ODIM + t + 64], a1);
    }
    out[g * ODIM + t]      = a0;
    out[g * ODIM + t + 64] = a1;
  }
}

extern "C" void kernel_launch(void* const* d_in, const int* in_sizes, int n_in,
                              void* d_out, int out_size, void* d_ws, size_t ws_size,
                              hipStream_t stream) {
  const float* x    = (const float*)d_in[0];
  const int*   adj  = (const int*)d_in[1];
  const float* W_in = (const float*)d_in[2];
  const float* b_in = (const float*)d_in[3];
  const float* Wq   = (const float*)d_in[4];
  const float* Wk   = (const float*)d_in[5];
  const float* Wv   = (const float*)d_in[6];
  const float* Wo   = (const float*)d_in[7];
  const float* bo   = (const float*)d_in[8];
  const float* lng  = (const float*)d_in[9];
  const float* lnb  = (const float*)d_in[10];
  const float* Wp1  = (const float*)d_in[11];
  const float* bp1  = (const float*)d_in[12];
  const float* Wp2  = (const float*)d_in[13];
  const float* bp2  = (const float*)d_in[14];
  float* outp = (float*)d_out;
  u16*   wsW  = (u16*)d_ws;

  hipLaunchKernelGGL(prep_pack, dim3(NW + 2), dim3(256), 0, stream,
                     Wq, Wk, Wv, Wo, W_in, adj, wsW);
  hipLaunchKernelGGL(gnn_fused, dim3(BTOT / NWAVE), dim3(NTH), 0, stream,
                     x, b_in, wsW, bo, lng, lnb, Wp1, bp1, Wp2, bp2, outp);
}

// Round 8
// 239.810 us; speedup vs baseline: 1.2259x; 1.0475x over previous
//
#include <hip/hip_runtime.h>
#include <stdint.h>

// Problem constants
#define NB       64
#define FIN      12
#define HD       64
#define NHEADS   4
#define DHEAD    16
#define NLAYERS  3
#define ODIM     128
#define LN_EPS   1e-5f
#define BTOT     8192

#define NTH      256   // 4 independent waves per block; ONE WAVE = ONE GRAPH
#define NWAVE    4
#define NW       (NLAYERS * 4)
#define WFRAG    4096  // u16 per packed weight
#define WIN_U16  2048  // packed W_in^T (zero-padded K=32)
#define NTILES   10    // band tiles (|tj-ti|<=1) of the 4x4 tile grid
#define MSK_U32  (NTILES * 64 * 2)   // 1280 u32 of f16 0/1 fragment masks

typedef unsigned int       u32;
typedef unsigned short     u16;
typedef unsigned long long u64;
typedef _Float16           f16;

typedef f16    f16x8 __attribute__((ext_vector_type(8)));
typedef f16    f16x4 __attribute__((ext_vector_type(4)));
typedef f16    h2    __attribute__((ext_vector_type(2)));
typedef __fp16 hh2   __attribute__((ext_vector_type(2)));
typedef float  f32x4 __attribute__((ext_vector_type(4)));
union U128h { uint4 u; f16x8 v8; f16x4 v4h[2]; h2 v2[4]; };
union U64h  { uint2 u; f16x4 v4; h2 h[2]; u32 w[2]; u16 s[4]; };

#if __has_builtin(__builtin_amdgcn_exp2f)
  __device__ __forceinline__ float e2(float x) { return __builtin_amdgcn_exp2f(x); }
#else
  __device__ __forceinline__ float e2(float x) { return exp2f(x); }
#endif

__device__ __forceinline__ float fdot2h(h2 a, h2 b, float c) {
#if __has_builtin(__builtin_amdgcn_fdot2)
  return __builtin_amdgcn_fdot2(a, b, c, false);
#else
  return c + (float)a[0] * (float)b[0] + (float)a[1] * (float)b[1];
#endif
}

#if __has_builtin(__builtin_amdgcn_cvt_pkrtz)
__device__ __forceinline__ u32 packh2(float a, float b) {
  hh2 p = __builtin_amdgcn_cvt_pkrtz(a, b);
  return *(u32*)&p;
}
#else
__device__ __forceinline__ u32 packh2(float a, float b) {
  h2 p = {(f16)a, (f16)b};
  return *(u32*)&p;
}
#endif

#if __has_builtin(__builtin_amdgcn_mfma_f32_16x16x16f16)
__device__ __forceinline__ f32x4 mfma16(f16x4 a, f16x4 b, f32x4 c) {
  return __builtin_amdgcn_mfma_f32_16x16x16f16(a, b, c, 0, 0, 0);
}
#elif __has_builtin(__builtin_amdgcn_mfma_f32_16x16x16_f16)
__device__ __forceinline__ f32x4 mfma16(f16x4 a, f16x4 b, f32x4 c) {
  return __builtin_amdgcn_mfma_f32_16x16x16_f16(a, b, c, 0, 0, 0);
}
#else
__device__ __forceinline__ f32x4 mfma16(f16x4 a, f16x4 b, f32x4 c) {
  f16x8 a8 = {a[0], a[1], a[2], a[3], (f16)0, (f16)0, (f16)0, (f16)0};
  f16x8 b8 = {b[0], b[1], b[2], b[3], (f16)0, (f16)0, (f16)0, (f16)0};
  return __builtin_amdgcn_mfma_f32_16x16x32_f16(a8, b8, c, 0, 0, 0);
}
#endif

__device__ __forceinline__ f32x4 mfma32(f16x8 a, f16x8 b, f32x4 c) {
  return __builtin_amdgcn_mfma_f32_16x16x32_f16(a, b, c, 0, 0, 0);
}

__device__ __forceinline__ f16x4 pa4(u32 w0, u32 w1) {
  U64h u; u.w[0] = w0; u.w[1] = w1; return u.v4;
}

// NO activation LDS. Masks (block-shared, read-only) + per-wave MLP scratch.
struct __align__(16) Smem {
  u32   Msk[MSK_U32];        // 5120 B
  float scr[NWAVE][128];     // per-wave: pooled[64] + y1[64]
};  // 7168 B

// ---------------- prep: Wq/Wk/Wo packed in mmT B-fragment order (Wq carries
// softmax scale*log2e); Wv packed for the DIRECT orientation (V = H @ Wv) so
// the PV V^T A-fragment falls out of the GEMM with zero shuffles; W_in^T
// (K zero-padded to 32); adjacency as f16 0/1 fragment masks.
extern "C" __global__ void __launch_bounds__(256)
prep_pack(const float* __restrict__ Wq, const float* __restrict__ Wk,
          const float* __restrict__ Wv, const float* __restrict__ Wo,
          const float* __restrict__ W_in, const int* __restrict__ adj,
          u16* __restrict__ wsW) {
  const int w = blockIdx.x;
  if (w < NW) {
    const int l = w >> 2, ty = w & 3;
    u16* dst = wsW + w * WFRAG;
    if (ty == 2) {
      // direct-orientation Wv: frag fi = dt*2+c; elem e: kk = c*2+(e>>2), j=e&3
      // value = Wv[kk*16 + q*4 + j][dt*16 + m]  (B-frag lane (m,q))
      const float* src = Wv + l * HD * HD;
      for (int f = threadIdx.x; f < 512; f += 256) {
        const int lane = f & 63, fi = f >> 6;
        const int dt = fi >> 1, c = fi & 1;
        const int mm = lane & 15, mq = (lane >> 4) & 3;
        u16 tmp[8];
        #pragma unroll
        for (int e = 0; e < 8; ++e) {
          const int kk = c * 2 + (e >> 2), j = e & 3;
          f16 hv = (f16)src[(kk * 16 + mq * 4 + j) * HD + dt * 16 + mm];
          tmp[e] = *(u16*)&hv;
        }
        *(uint4*)(dst + f * 8) = *(const uint4*)tmp;
      }
    } else {
      const float* src = (ty == 0 ? Wq : ty == 1 ? Wk : Wo) + l * HD * HD;
      const float sc = (ty == 0) ? (0.25f * 1.44269504f) : 1.0f;
      for (int f = threadIdx.x; f < 512; f += 256) {
        const int lane = f & 63, kh = (f >> 6) & 1, nt = f >> 7;
        const int n  = nt * 16 + (lane & 15);
        const int k0 = kh * 32 + ((lane >> 4) & 3) * 8;
        u16 tmp[8];
        #pragma unroll
        for (int j = 0; j < 8; ++j) {
          f16 hv = (f16)(src[(k0 + j) * HD + n] * sc);
          tmp[j] = *(u16*)&hv;
        }
        *(uint4*)(dst + f * 8) = *(const uint4*)tmp;
      }
    }
  } else if (w == NW) {
    const int t = threadIdx.x;
    const int mt = t >> 6, lane = t & 63;
    const int mm = lane & 15, qq = (lane >> 4) & 3;
    u16 tmp[8];
    #pragma unroll
    for (int j = 0; j < 8; ++j) {
      const int k = qq * 8 + j;
      f16 hv = (k < FIN) ? (f16)W_in[k * HD + mt * 16 + mm] : (f16)0.0f;
      tmp[j] = *(u16*)&hv;
    }
    *(uint4*)(wsW + NW * WFRAG + t * 8) = *(const uint4*)tmp;
  } else {
    static const int TIv[NTILES] = {0, 0, 1, 1, 1, 2, 2, 2, 3, 3};
    static const int TJv[NTILES] = {0, 1, 0, 1, 2, 1, 2, 3, 2, 3};
    u32* wsMsk = (u32*)(wsW + NW * WFRAG + WIN_U16);
    for (int idx = threadIdx.x; idx < MSK_U32; idx += 256) {
      const int tile = idx >> 7, rem = idx & 127;
      const int l = rem >> 1, pr = rem & 1;
      const int i  = TIv[tile] * 16 + (l & 15);
      const int j0 = TJv[tile] * 16 + ((l >> 4) & 3) * 4 + pr * 2;
      const u32 lo = (adj[i * NB + j0]     != 0) ? 0x3C00u : 0u;
      const u32 hi = (adj[i * NB + j0 + 1] != 0) ? 0x3C00u : 0u;
      wsMsk[idx] = lo | (hi << 16);
    }
  }
}

// B-fragment builder from 8 pre-packed h2 words (p[2*mt+c] = feats mt*16+q*4+
// {2c,2c+1} of the lane's node). Verified shuffle-transpose (5 rounds in prod).
__device__ __forceinline__ void mb_from_p(const u32 p[8], int q, int m,
                                          U128h& b0, U128h& b1) {
  const int sA = (2 * (q & 1)) * 16 + m;
  const int sB = sA + 16;
  u32 A[8], B[8];
  #pragma unroll
  for (int k = 0; k < 8; ++k) A[k] = (u32)__shfl((int)p[k], sA, 64);
  #pragma unroll
  for (int k = 0; k < 8; ++k) B[k] = (u32)__shfl((int)p[k], sB, 64);
  const bool hi = (q & 2) != 0;
  b0.u.x = hi ? A[2] : A[0];  b0.u.y = hi ? A[3] : A[1];
  b0.u.z = hi ? B[2] : B[0];  b0.u.w = hi ? B[3] : B[1];
  b1.u.x = hi ? A[6] : A[4];  b1.u.y = hi ? A[7] : A[5];
  b1.u.z = hi ? B[6] : B[4];  b1.u.w = hi ? B[7] : B[5];
}

extern "C" __global__ void __launch_bounds__(NTH, 2)
gnn_fused(const float* __restrict__ x, const float* __restrict__ b_in,
          const u16* __restrict__ wsW, const float* __restrict__ bo,
          const float* __restrict__ ln_g, const float* __restrict__ ln_b,
          const float* __restrict__ Wp1, const float* __restrict__ bp1,
          const float* __restrict__ Wp2, const float* __restrict__ bp2,
          float* __restrict__ out) {
  __shared__ Smem s;
  const int tb = threadIdx.x;
  const int t  = tb & 63;                // lane within wave
  const int wv = tb >> 6;                // wave id
  const int m  = t & 15, q = t >> 4;
  const int g  = (int)blockIdx.x * NWAVE + wv;   // graph id (one per wave)

  const u16* wsWin = wsW + NW * WFRAG;

  // stage masks (block-shared, layer/head/graph-invariant); sole block barrier
  {
    const uint4* mg4 = (const uint4*)(wsWin + WIN_U16);
    if (tb < 256) ((uint4*)s.Msk)[tb] = mg4[tb];
    if (tb < 64)  ((uint4*)s.Msk)[256 + tb] = mg4[256 + tb];
  }
  __syncthreads();

  // ---------------- input projection: h^T = W_in^T @ x^T (K=32 padded),
  // x B-frags built straight from global (lane (m,q) supplies feats q*8+j).
  f32x4 hr[4][4];   // hr[ng][mt]: h[node = ng*16+m][feat = mt*16 + q*4 + r]
  {
    #pragma unroll
    for (int ng = 0; ng < 4; ++ng) {
      U128h xb;
      xb.u = make_uint4(0u, 0u, 0u, 0u);
      const float* gx = x + (size_t)(g * NB + ng * 16 + m) * FIN;
      if (q == 0) {
        const float4 fa = *(const float4*)gx;
        const float4 fb = *(const float4*)(gx + 4);
        xb.u = make_uint4(packh2(fa.x, fa.y), packh2(fa.z, fa.w),
                          packh2(fb.x, fb.y), packh2(fb.z, fb.w));
      } else if (q == 1) {
        const float4 fc = *(const float4*)(gx + 8);
        xb.u.x = packh2(fc.x, fc.y);
        xb.u.y = packh2(fc.z, fc.w);
      }
      #pragma unroll
      for (int mt = 0; mt < 4; ++mt) {
        U128h aw;
        aw.u = *(const uint4*)(wsWin + (mt * 64 + t) * 8);
        f32x4 acc = {0.f, 0.f, 0.f, 0.f};
        acc = mfma32(aw.v8, xb.v8, acc);
        const f32x4 b4 = *(const f32x4*)&b_in[mt * 16 + q * 4];
        hr[ng][mt] = acc + b4;
      }
    }
  }

  // ---------------- transformer layers: wave-autonomous, NO barriers,
  // NO activation LDS. Weight fragments software-pipelined one phase ahead
  // (r8): each matrix's 8 b128 loads issue a full compute phase before use,
  // hiding ~300cy L2 latency under MFMA/VALU work. <=2 matrices in flight.
  #pragma unroll 1
  for (int l = 0; l < NLAYERS; ++l) {
    const u16* wq  = wsW + (l * 4 + 0) * WFRAG;
    const u16* wk  = wsW + (l * 4 + 1) * WFRAG;
    const u16* wvd = wsW + (l * 4 + 2) * WFRAG;
    const u16* wo  = wsW + (l * 4 + 3) * WFRAG;
    const f32x4 z4 = {0.f, 0.f, 0.f, 0.f};

    // Issue V-weights (needed first) and Q-weights (needed 2 phases out) now.
    U128h aV[8], aQ[8];
    #pragma unroll
    for (int i = 0; i < 8; ++i) aV[i].u = *(const uint4*)(wvd + (i * 64 + t) * 8);
    #pragma unroll
    for (int i = 0; i < 8; ++i) aQ[i].u = *(const uint4*)(wq + (i * 64 + t) * 8);

    // packed h words: hp[ng][2*mt+c] = f16x2(hr[ng][mt][2c], [2c+1]).
    // Doubles as the V-GEMM A-fragment. (VALU work overlapping aV/aQ latency.)
    u32 hp[4][8];
    #pragma unroll
    for (int ng = 0; ng < 4; ++ng)
      #pragma unroll
      for (int mt = 0; mt < 4; ++mt) {
        hp[ng][2 * mt]     = packh2(hr[ng][mt][0], hr[ng][mt][1]);
        hp[ng][2 * mt + 1] = packh2(hr[ng][mt][2], hr[ng][mt][3]);
      }

    // V = H @ Wv (direct)  ->  vf[hh][kt] = V[kt*16+q*4+j][hh*16+m]
    // = exactly the V^T A-fragment PV needs: zero-shuffle V transpose.
    U64h vf[4][4];
    #pragma unroll
    for (int dt = 0; dt < 4; ++dt) {
      #pragma unroll
      for (int nt = 0; nt < 4; ++nt) {
        f32x4 acc = z4;
        acc = mfma16(pa4(hp[nt][0], hp[nt][1]), aV[dt * 2].v4h[0], acc);
        acc = mfma16(pa4(hp[nt][2], hp[nt][3]), aV[dt * 2].v4h[1], acc);
        acc = mfma16(pa4(hp[nt][4], hp[nt][5]), aV[dt * 2 + 1].v4h[0], acc);
        acc = mfma16(pa4(hp[nt][6], hp[nt][7]), aV[dt * 2 + 1].v4h[1], acc);
        vf[dt][nt].w[0] = packh2(acc[0], acc[1]);
        vf[dt][nt].w[1] = packh2(acc[2], acc[3]);
      }
    }
    // aV dead. Issue K-weights; latency hides under hb + Q phase.
    U128h aK[8];
    #pragma unroll
    for (int i = 0; i < 8; ++i) aK[i].u = *(const uint4*)(wk + (i * 64 + t) * 8);

    // h B-fragments (shuffle transpose); hp dead after this.
    U128h hb[4][2];
    #pragma unroll
    for (int ng = 0; ng < 4; ++ng) mb_from_p(hp[ng], q, m, hb[ng][0], hb[ng][1]);

    // Q^T = Wq^T @ H^T  ->  qf[hh][ti] = Q[ti*16+m][hh*16+q*4+j]
    U64h qf[4][4];
    #pragma unroll
    for (int mt = 0; mt < 4; ++mt) {
      #pragma unroll
      for (int ng = 0; ng < 4; ++ng) {
        f32x4 acc = z4;
        acc = mfma32(aQ[mt * 2].v8,     hb[ng][0].v8, acc);
        acc = mfma32(aQ[mt * 2 + 1].v8, hb[ng][1].v8, acc);
        qf[mt][ng].w[0] = packh2(acc[0], acc[1]);
        qf[mt][ng].w[1] = packh2(acc[2], acc[3]);
      }
    }
    // aQ dead. Issue Wo-weights; latency hides under K + attention phases.
    U128h aO[8];
    #pragma unroll
    for (int i = 0; i < 8; ++i) aO[i].u = *(const uint4*)(wo + (i * 64 + t) * 8);

    // K^T = Wk^T @ H^T  ->  kf[hh][tj] = K[tj*16+m][hh*16+q*4+j]; hb dead after.
    U64h kf[4][4];
    #pragma unroll
    for (int mt = 0; mt < 4; ++mt) {
      #pragma unroll
      for (int ng = 0; ng < 4; ++ng) {
        f32x4 acc = z4;
        acc = mfma32(aK[mt * 2].v8,     hb[ng][0].v8, acc);
        acc = mfma32(aK[mt * 2 + 1].v8, hb[ng][1].v8, acc);
        kf[mt][ng].w[0] = packh2(acc[0], acc[1]);
        kf[mt][ng].w[1] = packh2(acc[2], acc[3]);
      }
    }

    // ---- band-tile attention, all 4 heads in-wave.
    // S^T = K·Q^T ; P masked via f16 0/1 frags; O^T = V^T·P^T.
    // O lands node<->m (same as h); rinv folded into the f16 pack (opk).
    u32 opk[4][8];   // opk[ti][2*hh+c]: packed O, ready for mb_from_p
    {
      const h2 one2 = {(f16)1.0f, (f16)1.0f};
#define ATTN_HT(HH, TI, TJ0, NTJ, T0)                                          \
      {                                                                        \
        f32x4 ot = z4;                                                         \
        float dsum = 0.0f;                                                     \
        _Pragma("unroll")                                                      \
        for (int dt = 0; dt < (NTJ); ++dt) {                                   \
          const int tj = (TJ0) + dt;                                           \
          f32x4 st = mfma16(kf[HH][tj].v4, qf[HH][TI].v4, z4);                 \
          const uint2 mmv = *(const uint2*)&s.Msk[((T0) + dt) * 128 + (t << 1)]; \
          U64h pp;                                                             \
          pp.w[0] = packh2(e2(st[0]), e2(st[1]));                              \
          pp.w[1] = packh2(e2(st[2]), e2(st[3]));                              \
          pp.h[0] *= *(const h2*)&mmv.x;                                       \
          pp.h[1] *= *(const h2*)&mmv.y;                                       \
          dsum = fdot2h(pp.h[0], one2, dsum);                                  \
          dsum = fdot2h(pp.h[1], one2, dsum);                                  \
          ot = mfma16(vf[HH][tj].v4, pp.v4, ot);                               \
        }                                                                      \
        dsum += __shfl_xor(dsum, 16, 64);                                      \
        dsum += __shfl_xor(dsum, 32, 64);                                      \
        const float rinv = 1.0f / dsum;                                        \
        opk[TI][2 * (HH)]     = packh2(ot[0] * rinv, ot[1] * rinv);            \
        opk[TI][2 * (HH) + 1] = packh2(ot[2] * rinv, ot[3] * rinv);            \
      }
      #pragma unroll
      for (int hh = 0; hh < 4; ++hh) {
        ATTN_HT(hh, 0, 0, 2, 0)
        ATTN_HT(hh, 1, 0, 3, 2)
        ATTN_HT(hh, 2, 1, 3, 5)
        ATTN_HT(hh, 3, 2, 2, 8)
      }
#undef ATTN_HT
    }

    // u^T = Wo^T @ O^T + h + bo ; LN over feats (q-lane reduce). O B-frags via
    // the same verified mb_from_p (opk has identical register form to hp).
    {
      #pragma unroll
      for (int ng = 0; ng < 4; ++ng) {
        U128h ob0, ob1;
        mb_from_p(opk[ng], q, m, ob0, ob1);
        float s1 = 0.0f, s2 = 0.0f;
        #pragma unroll
        for (int mt = 0; mt < 4; ++mt) {
          f32x4 acc = z4;
          acc = mfma32(aO[mt * 2].v8,     ob0.v8, acc);
          acc = mfma32(aO[mt * 2 + 1].v8, ob1.v8, acc);
          const f32x4 bo4 = *(const f32x4*)&bo[l * HD + mt * 16 + q * 4];
          const f32x4 u4 = hr[ng][mt] + acc + bo4;
          hr[ng][mt] = u4;
          #pragma unroll
          for (int r = 0; r < 4; ++r) { s1 += u4[r]; s2 += u4[r] * u4[r]; }
        }
        s1 += __shfl_xor(s1, 16, 64); s1 += __shfl_xor(s1, 32, 64);
        s2 += __shfl_xor(s2, 16, 64); s2 += __shfl_xor(s2, 32, 64);
        const float mu  = s1 * (1.0f / 64.0f);
        const float var = s2 * (1.0f / 64.0f) - mu * mu;
        const float rs  = rsqrtf(var + LN_EPS);
        #pragma unroll
        for (int mt = 0; mt < 4; ++mt) {
          const f32x4 g4  = *(const f32x4*)&ln_g[l * HD + mt * 16 + q * 4];
          const f32x4 be4 = *(const f32x4*)&ln_b[l * HD + mt * 16 + q * 4];
          #pragma unroll
          for (int r = 0; r < 4; ++r)
            hr[ng][mt][r] = (hr[ng][mt][r] - mu) * rs * g4[r] + be4[r];
        }
      }
    }
  }

  // ---------------- head: pool (in-lane ng-sum + m-lane butterfly), MLP via
  // per-wave 512 B scratch. All wave-internal: program order, no barriers.
  {
    #pragma unroll
    for (int mt = 0; mt < 4; ++mt) {
      f32x4 v = hr[0][mt] + hr[1][mt] + hr[2][mt] + hr[3][mt];
      #pragma unroll
      for (int r = 0; r < 4; ++r) {
        float vv = v[r];
        vv += __shfl_xor(vv, 1, 64); vv += __shfl_xor(vv, 2, 64);
        vv += __shfl_xor(vv, 4, 64); vv += __shfl_xor(vv, 8, 64);
        v[r] = vv * (1.0f / 64.0f);
      }
      if (m == 0) *(f32x4*)&s.scr[wv][mt * 16 + q * 4] = v;
    }
  }
  {
    float acc = bp1[t];
    #pragma unroll 8
    for (int k = 0; k < HD; ++k) acc = fmaf(s.scr[wv][k], Wp1[k * HD + t], acc);
    s.scr[wv][64 + t] = fmaxf(acc, 0.0f);
  }
  {
    float a0 = bp2[t], a1 = bp2[t + 64];
    #pragma unroll 8
    for (int c = 0; c < HD; ++c) {
      const float yc = s.scr[wv][64 + c];
      a0 = fmaf(yc, Wp2[c * ODIM + t], a0);
      a1 = fmaf(yc, Wp2[c * ODIM + t + 64], a1);
    }
    out[g * ODIM + t]      = a0;
    out[g * ODIM + t + 64] = a1;
  }
}

extern "C" void kernel_launch(void* const* d_in, const int* in_sizes, int n_in,
                              void* d_out, int out_size, void* d_ws, size_t ws_size,
                              hipStream_t stream) {
  const float* x    = (const float*)d_in[0];
  const int*   adj  = (const int*)d_in[1];
  const float* W_in = (const float*)d_in[2];
  const float* b_in = (const float*)d_in[3];
  const float* Wq   = (const float*)d_in[4];
  const float* Wk   = (const float*)d_in[5];
  const float* Wv   = (const float*)d_in[6];
  const float* Wo   = (const float*)d_in[7];
  const float* bo   = (const float*)d_in[8];
  const float* lng  = (const float*)d_in[9];
  const float* lnb  = (const float*)d_in[10];
  const float* Wp1  = (const float*)d_in[11];
  const float* bp1  = (const float*)d_in[12];
  const float* Wp2  = (const float*)d_in[13];
  const float* bp2  = (const float*)d_in[14];
  float* outp = (float*)d_out;
  u16*   wsW  = (u16*)d_ws;

  hipLaunchKernelGGL(prep_pack, dim3(NW + 2), dim3(256), 0, stream,
                     Wq, Wk, Wv, Wo, W_in, adj, wsW);
  hipLaunchKernelGGL(gnn_fused, dim3(BTOT / NWAVE), dim3(NTH), 0, stream,
                     x, b_in, wsW, bo, lng, lnb, Wp1, bp1, Wp2, bp2, outp);
}